// Round 1
// baseline (143.338 us; speedup 1.0000x reference)
//
#include <hip/hip_runtime.h>
#include <hip/hip_bf16.h>

// CIN (xDeepFM) fused 3-layer kernel for MI355X — R13: R12 + W staged
// through LDS for L0/L1 (double-buffered global_load_lds, m97 pattern).
// R12 post-mortem: MfmaUtil 32% == 22us MFMA-pipe busy vs 20.5us floor ->
// stalls, not pipe. Per-phase L2 demand of the per-wave register W path:
// L0 64, L1 64, L2step2 128 B/cyc/CU vs ~58 B/cyc/CU L2 ceiling — every
// phase at/over the L2 roofline; with 2 waves/SIMD the loads can't be
// hidden. Fix: stage each L1 field (32KB) / L0 quad (16KB) once per WG
// into LDS via 16B global_load_lds DMA (halves L0/L1 L2 traffic — the two
// npair waves shared nothing before) and consume via contiguous
// ds_read_b128 (lgkm, short deterministic latency; vmcnt queue = pure DMA
// prefetch hidden under the previous chunk's ~1024cy of MFMA).
// Step2 (W2 1MB/CU, no duplication) kept on the register path this round.
// Grid: 256 WGs x 512 thr = 1 WG/CU, 8 waves = 2/SIMD. LDS 112KB.

typedef __attribute__((ext_vector_type(8))) short short8;
typedef __attribute__((ext_vector_type(8))) __bf16 bf16x8;
typedef __attribute__((ext_vector_type(16))) float f32x16;
typedef __attribute__((ext_vector_type(4))) unsigned short u16x4;

#define DEVINL static __device__ __forceinline__

DEVINL unsigned short f2bf_rne(float f) {
  unsigned int u = __builtin_bit_cast(unsigned int, f);
  unsigned int r = u + 0x7fffu + ((u >> 16) & 1u);
  return (unsigned short)(r >> 16);
}

// async global->LDS, 16B per lane; LDS dest = wave-uniform base + lane*16
DEVINL void gload_lds16(const void* g, void* l) {
  __builtin_amdgcn_global_load_lds(
      (const __attribute__((address_space(1))) unsigned int*)g,
      (__attribute__((address_space(3))) unsigned int*)l, 16, 0, 0);
}

// MFMA adapter: builtin may want v8i16 or v8bf16. SFINAE both.
template <typename V>
DEVINL auto mfma_32x32x16_bf16(V a, V b, f32x16 c, int)
    -> decltype(__builtin_amdgcn_mfma_f32_32x32x16_bf16(a, b, c, 0, 0, 0)) {
  return __builtin_amdgcn_mfma_f32_32x32x16_bf16(a, b, c, 0, 0, 0);
}
template <typename V>
DEVINL f32x16 mfma_32x32x16_bf16(V a, V b, f32x16 c, long) {
  return __builtin_amdgcn_mfma_f32_32x32x16_bf16(
      __builtin_bit_cast(bf16x8, a), __builtin_bit_cast(bf16x8, b), c, 0, 0, 0);
}
DEVINL f32x16 mfma_bf16(short8 a, short8 b, f32x16 c) {
  return mfma_32x32x16_bf16(a, b, c, 0);
}

// ---------------- W pack kernel (unchanged, verified R2-R12) ----------------
// Packed layout per layer: [f][kb=k>>3][h][j=k&7] bf16 (granule = 1024 u16).
__global__ void pack_w_kernel(const float* __restrict__ W0,
                              const float* __restrict__ W1,
                              const float* __restrict__ W2,
                              unsigned short* __restrict__ Wt) {
  __shared__ float tile[8][132];
  const int u = blockIdx.x;
  const float* W; int FK, f, kb, base;
  if (u < 128)      { W = W0; FK = 32;  f = u >> 2;         kb = u & 3;          base = 0; }
  else if (u < 640) { W = W1; FK = 128; f = (u - 128) >> 4; kb = (u - 128) & 15; base = 131072; }
  else              { W = W2; FK = 128; f = (u - 640) >> 4; kb = (u - 640) & 15; base = 655360; }
  const int t = threadIdx.x;
#pragma unroll
  for (int i = 0; i < 4; ++i) {
    const int e = t + i * 256;  // 0..1023
    const int kk = e >> 7, h = e & 127;
    tile[kk][h] = W[(f * FK + kb * 8 + kk) * 128 + h];
  }
  __syncthreads();
  unsigned short* dst = Wt + base + f * (FK / 8) * 1024 + kb * 1024;
  const int h = t >> 1;
  const int j0 = (t & 1) * 4;
  u16x4 v;
  v.x = f2bf_rne(tile[j0 + 0][h]);
  v.y = f2bf_rne(tile[j0 + 1][h]);
  v.z = f2bf_rne(tile[j0 + 2][h]);
  v.w = f2bf_rne(tile[j0 + 3][h]);
  *(u16x4*)&dst[t * 4] = v;
}

// ---------------- layers 0/1: W staged to LDS, double-buffered -------------
// L1 chunk = 1 field = 32KB (granules 16f..16f+15); L0 chunk = 1 quad =
// 2 fields = 16KB. Stage chunk c+1 (DMA) -> compute chunk c (ds_read_b128
// frags + MFMA + x0 scale) -> __syncthreads (drain = chunk c+1 ready).
// Frag (qsel,i) of a chunk lives at u16 offset
//   qsel*8192 + i*2048 + half*1024 + (mrow*32+l31)*8
// — byte-identical to the old global layout relative to the chunk base.
template <int KQ, int LAYER>
DEVINL void run_layer(const unsigned short* __restrict__ WtL,
                      const float* __restrict__ bias,
                      const float* x0l,  // LDS-resident x0 block [b][f][d]
                      float* __restrict__ outp, int outoff,
                      unsigned int* SB, unsigned short* wlds,
                      int w, int lane, int mrow, int npair, int l31, int half) {
  __syncthreads();  // state in SB + x0l ready; wlds free (prev layer done)

  constexpr int NC   = (KQ == 8) ? 32 : 16;      // chunks in this layer
  constexpr int CU16 = (KQ == 8) ? 16384 : 8192; // u16 per chunk
  constexpr int LP   = (KQ == 8) ? 4 : 2;        // 1KB DMA loads / wave / chunk

  auto stage = [&](int c, int buf) {
#pragma unroll
    for (int j = 0; j < LP; ++j) {
      const int off = (w * LP + j) * 512;  // u16
      gload_lds16(WtL + (size_t)c * CU16 + off + lane * 8,
                  wlds + buf * CU16 + off);
    }
  };

  stage(0, 0);  // DMA lands under the sfr SB reads below

  // B-frags (S) from SB into registers, once per layer (unchanged R9).
  // slot (half,j) of sfr[nt][kq] holds S[r][k = kq*16 + half*8 + j],
  // r = npair*64 + nt*32 + l31. SB row k2=k/2 packs (k even lo16, k odd hi16).
  int4 sfr[2][KQ];
  const int rb = npair * 64;
#pragma unroll
  for (int nt = 0; nt < 2; ++nt) {
    const int r = rb + nt * 32 + l31;
#pragma unroll
    for (int kq = 0; kq < KQ; ++kq) {
      const int row0 = kq * 8 + half * 4;
      int4 v;
      v.x = (int)SB[(row0 + 0) * 128 + r];
      v.y = (int)SB[(row0 + 1) * 128 + r];
      v.z = (int)SB[(row0 + 2) * 128 + r];
      v.w = (int)SB[(row0 + 3) * 128 + r];
      sfr[nt][kq] = v;
    }
  }

  f32x16 zv;
#pragma unroll
  for (int e = 0; e < 16; ++e) zv[e] = 0.f;
  f32x16 outacc[2] = {zv, zv};

  __syncthreads();  // all waves hold sfr (SB free); chunk 0 staged (drain)

  const int hrow = mrow * 32 + l31;
  const int fro = half * 1024 + hrow * 8;  // frag u16 offset in granule pair
  const int xb0 = (npair * 2 + 0) * 1024 + l31;  // x0l[b_local][f][d=l31]
  const int xb1 = (npair * 2 + 1) * 1024 + l31;

#pragma unroll 1
  for (int c = 0; c < NC; ++c) {
    if (c + 1 < NC) stage(c + 1, (c + 1) & 1);
    const unsigned short* fb = wlds + (c & 1) * CU16;

    if constexpr (KQ == 8) {
      // chunk = field c
      const float xs0 = x0l[xb0 + c * 32];
      const float xs1 = x0l[xb1 + c * 32];
      f32x16 Y0, Y1;
#pragma unroll
      for (int kq = 0; kq < 8; ++kq) {
        const short8 wv =
            *(const short8*)&fb[(kq >> 2) * 8192 + (kq & 3) * 2048 + fro];
        const short8 s0 = __builtin_bit_cast(short8, sfr[0][kq]);
        const short8 s1 = __builtin_bit_cast(short8, sfr[1][kq]);
        Y0 = mfma_bf16(wv, s0, kq == 0 ? zv : Y0);
        Y1 = mfma_bf16(wv, s1, kq == 0 ? zv : Y1);
      }
#pragma unroll
      for (int e = 0; e < 16; ++e) {
        outacc[0][e] += xs0 * Y0[e];
        outacc[1][e] += xs1 * Y1[e];
      }
    } else {
      // chunk = quad c = fields (2c, 2c+1); frag i -> (field i>>1, kq i&1)
      const float xA0 = x0l[xb0 + (2 * c + 0) * 32];
      const float xA1 = x0l[xb1 + (2 * c + 0) * 32];
      const float xB0 = x0l[xb0 + (2 * c + 1) * 32];
      const float xB1 = x0l[xb1 + (2 * c + 1) * 32];
      const short8 s00 = __builtin_bit_cast(short8, sfr[0][0]);
      const short8 s01 = __builtin_bit_cast(short8, sfr[0][1]);
      const short8 s10 = __builtin_bit_cast(short8, sfr[1][0]);
      const short8 s11 = __builtin_bit_cast(short8, sfr[1][1]);
      short8 wv[4];
#pragma unroll
      for (int i = 0; i < 4; ++i)
        wv[i] = *(const short8*)&fb[i * 2048 + fro];
      f32x16 Y0 = mfma_bf16(wv[0], s00, zv);
      Y0 = mfma_bf16(wv[1], s01, Y0);
      f32x16 Y1 = mfma_bf16(wv[0], s10, zv);
      Y1 = mfma_bf16(wv[1], s11, Y1);
      f32x16 Z0 = mfma_bf16(wv[2], s00, zv);
      Z0 = mfma_bf16(wv[3], s01, Z0);
      f32x16 Z1 = mfma_bf16(wv[2], s10, zv);
      Z1 = mfma_bf16(wv[3], s11, Z1);
#pragma unroll
      for (int e = 0; e < 16; ++e) {
        outacc[0][e] += xA0 * Y0[e] + xB0 * Z0[e];
        outacc[1][e] += xA1 * Y1[e] + xB1 * Z1[e];
      }
    }
    __syncthreads();  // chunk c+1 staged; buf (c&1) free for stage(c+2)
  }

  // --- epilogue (unchanged R9) ---
  // C/D layout: col = lane&31 = n; row = (reg&3)+8*(reg>>2)+4*half = h.
  float bv[16];
#pragma unroll
  for (int e = 0; e < 16; ++e)
    bv[e] = bias[mrow * 32 + (e & 3) + 8 * (e >> 2) + 4 * half];

  if constexpr (LAYER < 2) {
    // next state S'[r][h] = bf16(acc+bias), packed [h/2][r] u32 into SB
#pragma unroll
    for (int nt = 0; nt < 2; ++nt) {
      const int r = rb + nt * 32 + l31;
#pragma unroll
      for (int g = 0; g < 4; ++g) {
        const int h2 = mrow * 16 + 4 * g + 2 * half;
        const float v0 = outacc[nt][4 * g + 0] + bv[4 * g + 0];
        const float v1 = outacc[nt][4 * g + 1] + bv[4 * g + 1];
        const float v2 = outacc[nt][4 * g + 2] + bv[4 * g + 2];
        const float v3 = outacc[nt][4 * g + 3] + bv[4 * g + 3];
        SB[h2 * 128 + r] =
            (unsigned)f2bf_rne(v0) | ((unsigned)f2bf_rne(v1) << 16);
        SB[(h2 + 1) * 128 + r] =
            (unsigned)f2bf_rne(v2) | ((unsigned)f2bf_rne(v3) << 16);
      }
    }
  }

  // final output: out[b, outoff+h] = sum_d acc + 32*bias (d = l31 lanes)
#pragma unroll
  for (int nt = 0; nt < 2; ++nt) {
    float sv[16];
#pragma unroll
    for (int e = 0; e < 16; ++e) {
      float v = outacc[nt][e];
      v += __shfl_xor(v, 1);
      v += __shfl_xor(v, 2);
      v += __shfl_xor(v, 4);
      v += __shfl_xor(v, 8);
      v += __shfl_xor(v, 16);
      sv[e] = v + 32.0f * bv[e];
    }
    if (l31 == 0) {
      const int b = npair * 2 + nt;
#pragma unroll
      for (int g = 0; g < 4; ++g) {
        const int h = mrow * 32 + 8 * g + 4 * half;
        float4 o = {sv[4 * g + 0], sv[4 * g + 1], sv[4 * g + 2], sv[4 * g + 3]};
        *(float4*)&outp[b * 384 + outoff + h] = o;
      }
    }
  }
}

// ---------------- layer 2, U-trick (unchanged R9/R12; register W path) -----
// out2[b,h] = sum_k U[b,k]*W2[k,h] + 32*b2[h];  U[b,f*128+g] = x0_b . S2_b^T.
DEVINL void run_layer2_fast(const unsigned short* __restrict__ WtL,
                            const float* __restrict__ bias,
                            const float* x0l,
                            float* __restrict__ outp,
                            unsigned int* SB, int wgb0,
                            int w, int l31, int half, int tid) {
  __syncthreads();  // S2 in SB ready ([g/2][r=b*32+d] u32 bf16-pairs)

  f32x16 zv;
#pragma unroll
  for (int e = 0; e < 16; ++e) zv[e] = 0.f;

  // ---- step 1: U = x0_b (32f x 32d) . S2_b^T (32d x 128g), MFMA M=f,N=g,K=d
  // wave w: batch bw = w>>1, g-half gh = w&1 (2 n-tiles of g).
  const int bw = w >> 1, gh = w & 1;
  short8 a1[2];  // A[m=f=l31][k=d slots], kq=0,1  (reads from LDS x0l)
  {
    const float* xr = &x0l[bw * 1024 + l31 * 32];
#pragma unroll
    for (int kq = 0; kq < 2; ++kq) {
      const int d0 = kq * 16 + half * 8;
      union { short8 v; unsigned short u[8]; } t;
#pragma unroll
      for (int j = 0; j < 8; ++j) t.u[j] = f2bf_rne(xr[d0 + j]);
      a1[kq] = t.v;
    }
  }
  short8 bfr[2][2];  // [nt][kq]: B[k=d][n=g]: S2[b, g, d]
#pragma unroll
  for (int nt = 0; nt < 2; ++nt) {
    const int g = gh * 64 + nt * 32 + l31;
    const unsigned int* row = &SB[(g >> 1) * 128 + bw * 32];
    const int sh = (g & 1) * 16;
#pragma unroll
    for (int kq = 0; kq < 2; ++kq) {
      const int d0 = kq * 16 + half * 8;
      union { short8 v; unsigned short u[8]; } t;
#pragma unroll
      for (int j = 0; j < 8; ++j)
        t.u[j] = (unsigned short)(row[d0 + j] >> sh);
      bfr[nt][kq] = t.v;
    }
  }
  f32x16 ua[2];
#pragma unroll
  for (int nt = 0; nt < 2; ++nt) {
    ua[nt] = mfma_bf16(a1[0], bfr[nt][0], zv);
    ua[nt] = mfma_bf16(a1[1], bfr[nt][1], ua[nt]);
  }
  __syncthreads();  // all waves done reading S2 from SB

  // ---- write U into SB as U32[k2 = k/2][b] (k = f*128+g; u16 writes) ----
  unsigned short* U16 = (unsigned short*)SB;
#pragma unroll
  for (int nt = 0; nt < 2; ++nt) {
    const int g = gh * 64 + nt * 32 + l31;
#pragma unroll
    for (int reg = 0; reg < 16; ++reg) {
      const int f = (reg & 3) + 8 * (reg >> 2) + 4 * half;
      const int k = f * 128 + g;
      U16[(k >> 1) * 8 + bw * 2 + (k & 1)] = f2bf_rne(ua[nt][reg]);
    }
  }
  __syncthreads();  // U ready

  // ---- step 2: D[m=h][n=b] = sum_k W2[k,h]*U[b,k]; wave: mt=w&3, kh=w>>2 ----
  const int mt = w & 3, kh = w >> 2;
  const char* gb = (const char*)WtL +
                   (size_t)(half * 2048 + (mt * 32 + l31) * 16);
  const int bl = l31 & 3;  // lanes 4..31 duplicate b (cols unused, bounds-safe)

  auto ldq2 = [&](short8* wv, int q) {  // quad q -> kq = 4q..4q+3
#pragma unroll
    for (int i = 0; i < 4; ++i)
      wv[i] = *(const short8*)(gb + (size_t)q * 16384 + i * 4096);
  };
  auto breadq = [&](short8* bv, int q) {  // B-frags for the 4 kq of quad q
#pragma unroll
    for (int i = 0; i < 4; ++i) {
      const int row0 = (q * 4 + i) * 8 + half * 4;
      int4 v;
      v.x = (int)SB[(row0 + 0) * 4 + bl];
      v.y = (int)SB[(row0 + 1) * 4 + bl];
      v.z = (int)SB[(row0 + 2) * 4 + bl];
      v.w = (int)SB[(row0 + 3) * 4 + bl];
      bv[i] = __builtin_bit_cast(short8, v);
    }
  };

  f32x16 acc0 = zv, acc1 = zv;
  short8 qa[4], qb[4], Ba[4], Bb[4];
  const int q0 = kh * 32;  // 32 quads = 128 kq per wave
  ldq2(qa, q0);
  breadq(Ba, q0);
#pragma unroll 1
  for (int qq = 0; qq < 16; ++qq) {
    const int q = q0 + 2 * qq;
    ldq2(qb, q + 1);
    breadq(Bb, q + 1);
#pragma unroll
    for (int i = 0; i < 4; ++i) acc0 = mfma_bf16(qa[i], Ba[i], acc0);
    if (qq < 15) {
      ldq2(qa, q + 2);
      breadq(Ba, q + 2);
    }
#pragma unroll
    for (int i = 0; i < 4; ++i) acc1 = mfma_bf16(qb[i], Bb[i], acc1);
  }
#pragma unroll
  for (int e = 0; e < 16; ++e) acc0[e] += acc1[e];

  __syncthreads();  // all waves done reading U from SB

  // ---- partials P[o = b*128 + h][kh] f32 into SB (4KB), then reduce ----
  float* P = (float*)SB;
  if (l31 < 4) {
#pragma unroll
    for (int reg = 0; reg < 16; ++reg) {
      const int h = mt * 32 + (reg & 3) + 8 * (reg >> 2) + 4 * half;
      P[(l31 * 128 + h) * 2 + kh] = acc0[reg];
    }
  }
  __syncthreads();
  {
    const int b = tid >> 7, h = tid & 127;  // tid 0..511 -> all outputs
    const float v = P[tid * 2] + P[tid * 2 + 1] + 32.0f * bias[h];
    outp[b * 384 + 256 + h] = v;
  }
}

__global__ __launch_bounds__(512, 1) void cin_kernel(
    const float* __restrict__ x0g, const unsigned short* __restrict__ Wt,
    const float* __restrict__ b0, const float* __restrict__ b1,
    const float* __restrict__ b2, float* __restrict__ out) {
  __shared__ unsigned int SB[64 * 128];                  // 32KB state/U/partials
  __shared__ __align__(16) float x0l[4096];              // 16KB x0 [b][f][d]
  __shared__ __align__(16) unsigned short wlds[32768];   // 64KB W double-buffer

  const int t = threadIdx.x;
  const int lane = t & 63;
  const int w = t >> 6;      // 0..7
  const int mrow = w & 3;    // h-tile of 32 (L0/L1)
  const int npair = w >> 2;  // batch pair (L0/L1)
  const int l31 = lane & 31, half = lane >> 5;
  const int wgb0 = blockIdx.x * 4;  // 4 batches per WG

  // prologue A: stage x0 block -> LDS via global_load_lds (16 chunks x 1KB)
  const float* xsrc = x0g + (size_t)wgb0 * 1024;
#pragma unroll
  for (int c = 0; c < 2; ++c) {
    const int chunk = w * 2 + c;
    gload_lds16(xsrc + chunk * 256 + lane * 4, x0l + chunk * 256);
  }
  // prologue B: S1 = bf16(x0^T) -> SB ([g/2][r] u32, r = b_local*32+d)
#pragma unroll
  for (int s = 0; s < 4; ++s) {
    const int i = t + s * 512;  // 0..2047
    const int r = i & 127, g2 = i >> 7;
    const float* p = &x0g[(wgb0 + (r >> 5)) * 1024 + (2 * g2) * 32 + (r & 31)];
    SB[g2 * 128 + r] =
        (unsigned)f2bf_rne(p[0]) | ((unsigned)f2bf_rne(p[32]) << 16);
  }
  // visibility handled by the entry barrier in run_layer (full drain)

  float* outp = out + (size_t)wgb0 * 384;
  run_layer<2, 0>(Wt, b0, x0l, outp, 0, SB, wlds, w, lane, mrow, npair, l31,
                  half);
  run_layer<8, 1>(Wt + 131072, b1, x0l, outp, 128, SB, wlds, w, lane, mrow,
                  npair, l31, half);
  run_layer2_fast(Wt + 655360, b2, x0l, outp, SB, wgb0, w, l31, half, t);
}

extern "C" void kernel_launch(void* const* d_in, const int* in_sizes, int n_in,
                              void* d_out, int out_size, void* d_ws, size_t ws_size,
                              hipStream_t stream) {
  (void)in_sizes; (void)n_in; (void)out_size; (void)ws_size;
  const float* x0 = (const float*)d_in[0];
  const float* W0 = (const float*)d_in[1];
  const float* W1 = (const float*)d_in[2];
  const float* W2 = (const float*)d_in[3];
  const float* b0 = (const float*)d_in[4];
  const float* b1 = (const float*)d_in[5];
  const float* b2 = (const float*)d_in[6];
  unsigned short* Wt = (unsigned short*)d_ws;  // 2,359,296 B

  pack_w_kernel<<<1152, 256, 0, stream>>>(W0, W1, W2, Wt);
  // 256 WGs x 512 thr = 1 WG/CU (8 waves, 2/SIMD)
  cin_kernel<<<256, 512, 0, stream>>>(x0, Wt, b0, b1, b2, (float*)d_out);
}